// Round 6
// baseline (331.497 us; speedup 1.0000x reference)
//
#include <hip/hip_runtime.h>

// Encoding layer. B=16, C=512, N=4096, K=32.
// R6: TLP experiment. Grid 1024 (b = blk>>6, chunk = blk&63; 64 tokens/block).
// 256 thr = 4 waves; wave pair (2g,2g+1) splits the C-contraction of token
// group g (c 0-255 / 256-511). LDS ~14 KB, cw A-frags in registers ->
// target 4 blocks/CU = 16 waves/CU (2x R4). Partials -> d_ws + reduce(64).

#define B_ 16
#define C_ 512
#define N_ 4096
#define K_ 32
#define WLS 40    // Wl row stride (u16)

typedef __attribute__((ext_vector_type(8))) short short8;
typedef __attribute__((ext_vector_type(16))) float floatx16;

__device__ inline unsigned short f2bf(float f) {
    union { float f; unsigned u; } v; v.f = f;
    unsigned r = v.u + 0x7FFFu + ((v.u >> 16) & 1u);  // RNE
    return (unsigned short)(r >> 16);
}

template <int USE_WS>
__global__ __launch_bounds__(256, 4)
void enc_kernel(const float* __restrict__ x, const float* __restrict__ cw,
                const float* __restrict__ scale, float* __restrict__ outp)
{
    __shared__ float Sred[2][32][33];            // combined S'[g][n][k], 8448 B
    __shared__ unsigned short Wl[2][K_ * WLS];   // softmax w bf16 [g][k][n], 5120 B
    __shared__ float xsqp[4][32];                // per-wave ||x||^2 halves
    __shared__ float csq[K_];
    __shared__ float scl[K_];

    const int tid  = threadIdx.x;
    const int wave = tid >> 6;
    const int lane = tid & 63;
    const int l31  = lane & 31;
    const int lh   = lane >> 5;

    const int b     = blockIdx.x >> 6;
    const int chunk = blockIdx.x & 63;
    const int g     = wave >> 1;          // token group 0/1
    const int coff  = (wave & 1) * 256;   // c-half of this wave
    const float* xb = x + (long)b * C_ * N_;

    // ---- GEMM1 ring prefetch: 3 stages, issued first ----
    const int n0 = chunk * 64 + g * 32;
    const float* xg = xb + n0 + l31;
    float xv[3][16];
#define G1LOAD(st_, sp_)                                                       \
    { _Pragma("unroll")                                                        \
      for (int u = 0; u < 16; ++u)                                             \
          xv[st_][u] = xg[(long)(coff + (sp_) * 32 + (u >> 3) * 16             \
                                 + lh * 8 + (u & 7)) * N_]; }
    G1LOAD(0, 0)
    G1LOAD(1, 1)
    G1LOAD(2, 2)

    // ---- GEMM1 A-frags in registers: af[s][j] = cw[k=l31][coff+s*16+lh*8+j] ----
    short8 af[16];
    #pragma unroll
    for (int s = 0; s < 16; ++s) {
        const float4 a0 = *(const float4*)(cw + l31 * C_ + coff + s * 16 + lh * 8);
        const float4 a1 = *(const float4*)(cw + l31 * C_ + coff + s * 16 + lh * 8 + 4);
        af[s][0] = (short)f2bf(a0.x); af[s][1] = (short)f2bf(a0.y);
        af[s][2] = (short)f2bf(a0.z); af[s][3] = (short)f2bf(a0.w);
        af[s][4] = (short)f2bf(a1.x); af[s][5] = (short)f2bf(a1.y);
        af[s][6] = (short)f2bf(a1.z); af[s][7] = (short)f2bf(a1.w);
    }

    // ---- preamble: zero Sred, scale, csq ----
    if (tid < K_) scl[tid] = scale[tid];
    for (int i = tid; i < 2 * 32 * 33; i += 256) ((float*)Sred)[i] = 0.f;
    {
        const int k = tid >> 3, q = tid & 7;
        const float4* src = (const float4*)(cw + k * C_ + q * 64);
        float s = 0.f;
        #pragma unroll
        for (int i = 0; i < 16; ++i) {
            const float4 v = src[i];
            s += v.x*v.x + v.y*v.y + v.z*v.z + v.w*v.w;
        }
        s += __shfl_xor(s, 1); s += __shfl_xor(s, 2); s += __shfl_xor(s, 4);
        if (q == 0) csq[k] = s;
    }
    __syncthreads();   // A: Sred zeroed, csq/scl ready

    // ====== GEMM1: S[k][n] partial over this wave's 256-c half ======
    floatx16 S;
    #pragma unroll
    for (int i = 0; i < 16; ++i) S[i] = 0.f;
    float xsq = 0.f;

    #pragma unroll
    for (int sp = 0; sp < 8; ++sp) {
        const int st = sp % 3;
        #pragma unroll
        for (int h = 0; h < 2; ++h) {
            const int s = sp * 2 + h;
            short8 bx;
            #pragma unroll
            for (int j = 0; j < 8; ++j) {
                const float v = xv[st][h * 8 + j];
                xsq += v * v;
                bx[j] = (short)f2bf(v);
            }
            S = __builtin_amdgcn_mfma_f32_32x32x16_bf16(af[s], bx, S, 0, 0, 0);
        }
        if (sp + 3 < 8) G1LOAD(st, sp + 3)
    }
    xsq += __shfl_xor(xsq, 32);              // lh halves: same token, disjoint c
    if (lh == 0) xsqp[wave][l31] = xsq;

    // combine wave-pair partials
    #pragma unroll
    for (int r = 0; r < 16; ++r) {
        const int k = (r & 3) + 8 * (r >> 2) + 4 * lh;
        atomicAdd(&Sred[g][l31][k], S[r]);   // ds_add_f32
    }
    __syncthreads();   // B: Sred/xsqp combined

    // ---- softmax (waves 0,2 for their group; lane l31 = token) ----
    if ((wave & 1) == 0) {
        const float xq = xsqp[wave][l31] + xsqp[wave + 1][l31];
        float L[16], mx = -3.4e38f;
        #pragma unroll
        for (int r = 0; r < 16; ++r) {
            const int k = (r & 3) + 8 * (r >> 2) + 4 * lh;
            L[r] = scl[k] * (xq - 2.f * Sred[g][l31][k] + csq[k]);
            mx = fmaxf(mx, L[r]);
        }
        mx = fmaxf(mx, __shfl_xor(mx, 32));
        float sum = 0.f;
        #pragma unroll
        for (int r = 0; r < 16; ++r) { L[r] = __expf(L[r] - mx); sum += L[r]; }
        sum += __shfl_xor(sum, 32);
        const float inv = 1.f / sum;
        #pragma unroll
        for (int r = 0; r < 16; ++r) {
            const int k = (r & 3) + 8 * (r >> 2) + 4 * lh;
            Wl[g][k * WLS + l31] = f2bf(L[r] * inv);
        }
    }

    // ---- GEMM2 ring prefetch (addresses independent of Wl) ----
    float4 bv[3][2];
#define G2LOAD(bi_, i_)                                                        \
    { const int t_ = (i_) >> 2, st_ = (i_) & 3;                                \
      const int c_ = wave * 128 + t_ * 32 + l31;                               \
      const int no_ = (st_ >> 1) * 32 + (st_ & 1) * 16 + lh * 8;               \
      const float* p_ = xb + (long)c_ * N_ + chunk * 64 + no_;                 \
      bv[bi_][0] = *(const float4*)p_;                                         \
      bv[bi_][1] = *(const float4*)(p_ + 4); }
    G2LOAD(0, 0)
    G2LOAD(1, 1)
    G2LOAD(2, 2)

    __syncthreads();   // C: Wl ready

    // ====== GEMM2: enc[k][c] partial over this block's 64 tokens ======
    short8 aw[4];      // A[m=k=l31][kk=n]; identical across waves
    #pragma unroll
    for (int st = 0; st < 4; ++st)
        aw[st] = *(const short8*)&Wl[st >> 1][l31 * WLS + (st & 1) * 16 + lh * 8];

    floatx16 wacc;     // wsum[k] via ones-column MFMA (row layout matches acc)
    #pragma unroll
    for (int i = 0; i < 16; ++i) wacc[i] = 0.f;
    {
        short8 ones;
        #pragma unroll
        for (int j = 0; j < 8; ++j) ones[j] = (short)0x3F80;
        #pragma unroll
        for (int st = 0; st < 4; ++st)
            wacc = __builtin_amdgcn_mfma_f32_32x32x16_bf16(aw[st], ones, wacc, 0, 0, 0);
    }

    floatx16 acc[4];
    #pragma unroll
    for (int t = 0; t < 4; ++t)
        #pragma unroll
        for (int i = 0; i < 16; ++i) acc[t][i] = 0.f;

    #pragma unroll
    for (int i = 0; i < 16; ++i) {            // i = t*4 + st
        const int bi = i % 3;
        const int t  = i >> 2, st = i & 3;
        const float4 v0 = bv[bi][0];
        const float4 v1 = bv[bi][1];
        short8 bx;
        bx[0] = (short)f2bf(v0.x); bx[1] = (short)f2bf(v0.y);
        bx[2] = (short)f2bf(v0.z); bx[3] = (short)f2bf(v0.w);
        bx[4] = (short)f2bf(v1.x); bx[5] = (short)f2bf(v1.y);
        bx[6] = (short)f2bf(v1.z); bx[7] = (short)f2bf(v1.w);
        acc[t] = __builtin_amdgcn_mfma_f32_32x32x16_bf16(aw[st], bx, acc[t], 0, 0, 0);
        if (i + 3 < 16) G2LOAD(bi, i + 3)
    }

    // ---- epilogue: val = acc - wsum[k]*cw[k][c]; cw from global (L2-hot) ----
    float* dst = USE_WS ? (outp + (size_t)blockIdx.x * K_ * C_)
                        : (outp + (size_t)b * K_ * C_);
    #pragma unroll
    for (int t = 0; t < 4; ++t) {
        const int c = wave * 128 + t * 32 + l31;
        #pragma unroll
        for (int r = 0; r < 16; ++r) {
            const int k = (r & 3) + 8 * (r >> 2) + 4 * lh;
            const float val = acc[t][r] - wacc[r] * cw[k * C_ + c];
            if (USE_WS) dst[k * C_ + c] = val;
            else        atomicAdd(dst + k * C_ + c, val);
        }
    }
}

// out[b][k][c] = sum_{ch<64} part[b*64+ch][k][c];  grid 256 x 256, float4
__global__ __launch_bounds__(256)
void reduce_kernel(const float4* __restrict__ part, float4* __restrict__ out)
{
    const int gid = blockIdx.x * 256 + threadIdx.x;   // 0..65535
    const int bb  = gid >> 12;                        // 4096 float4 per batch
    const int i4  = gid & 4095;
    const float4* p = part + ((size_t)bb * 64) * 4096 + i4;
    float4 s = make_float4(0.f, 0.f, 0.f, 0.f);
    #pragma unroll
    for (int ch = 0; ch < 64; ++ch) {
        const float4 v = p[(size_t)ch * 4096];
        s.x += v.x; s.y += v.y; s.z += v.z; s.w += v.w;
    }
    out[gid] = s;
}

extern "C" void kernel_launch(void* const* d_in, const int* in_sizes, int n_in,
                              void* d_out, int out_size, void* d_ws, size_t ws_size,
                              hipStream_t stream) {
    const float* x     = (const float*)d_in[0];
    const float* cw    = (const float*)d_in[1];
    const float* scale = (const float*)d_in[2];
    float* out = (float*)d_out;

    const size_t ws_need = (size_t)1024 * K_ * C_ * sizeof(float);  // 64 MiB
    if (ws_size >= ws_need) {
        float* part = (float*)d_ws;
        hipLaunchKernelGGL(enc_kernel<1>, dim3(1024), dim3(256), 0, stream,
                           x, cw, scale, part);
        hipLaunchKernelGGL(reduce_kernel, dim3(256), dim3(256), 0, stream,
                           (const float4*)part, (float4*)out);
    } else {
        hipMemsetAsync(out, 0, (size_t)out_size * sizeof(float), stream);
        hipLaunchKernelGGL(enc_kernel<0>, dim3(1024), dim3(256), 0, stream,
                           x, cw, scale, out);
    }
}